// Round 12
// baseline (150.145 us; speedup 1.0000x reference)
//
#include <hip/hip_runtime.h>
#include <hip/hip_bf16.h>

// Fused causal self-attention (GQA) for MI355X/gfx950.
// Shapes: B=2, T=2048, C=1024, H=16, Hkv=4, D=64.
// Round 12: attn -> 1-wave blocks (no barriers), 2048 blocks heavy-first,
// 32x32 MFMA core (R11-verified algebra), K fragments direct from global
// (L2-resident, m169 lesson), V single-buffer wave-private LDS + reg prefetch.
// GEMMs/prep unchanged (R9-proven).

typedef __attribute__((ext_vector_type(8))) short s16x8;    // 8 x bf16 raw
typedef __attribute__((ext_vector_type(16))) float f32x16;  // 32x32 C/D
typedef __attribute__((ext_vector_type(4))) float f32x4;
typedef __attribute__((ext_vector_type(4))) unsigned short u16x4;
typedef __attribute__((ext_vector_type(4))) unsigned int u32x4;

#define LOG2E 1.44269504088896340736f

__device__ __forceinline__ float bf2f(unsigned short u) {
  unsigned int i = ((unsigned int)u) << 16;
  return __builtin_bit_cast(float, i);
}
__device__ __forceinline__ unsigned short f2bf(float f) {
  unsigned int i = __builtin_bit_cast(unsigned int, f);
  i += 0x7fffu + ((i >> 16) & 1u);   // RNE
  return (unsigned short)(i >> 16);
}
__device__ __forceinline__ unsigned int cvtpk(float lo, float hi) {
  unsigned int r;                    // low half <- lo, high half <- hi
  asm("v_cvt_pk_bf16_f32 %0, %1, %2" : "=v"(r) : "v"(lo), "v"(hi));
  return r;
}

__device__ __forceinline__ void async16(const void* g, void* l) {
  __builtin_amdgcn_global_load_lds(
      (const __attribute__((address_space(1))) void*)g,
      (__attribute__((address_space(3))) void*)l, 16, 0, 0);
}

// ---------------- prep kernels ----------------

__global__ void conv_f32_to_bf16(const float* __restrict__ in,
                                 unsigned short* __restrict__ out, int n) {
  int i = (blockIdx.x * blockDim.x + threadIdx.x) * 4;
  if (i + 3 < n) {
    float4 v = *(const float4*)(in + i);
    u16x4 o = { f2bf(v.x), f2bf(v.y), f2bf(v.z), f2bf(v.w) };
    *(u16x4*)(out + i) = o;
  }
}

// W [K][N] fp32 -> Wt [N][K] bf16
__global__ void transpose_conv(const float* __restrict__ W,
                               unsigned short* __restrict__ Wt, int K, int N) {
  __shared__ float tile[32][33];
  int n0 = blockIdx.x * 32, k0 = blockIdx.y * 32;
  int tx = threadIdx.x, ty = threadIdx.y;
  for (int i = ty; i < 32; i += 8)
    tile[i][tx] = W[(size_t)(k0 + i) * N + n0 + tx];
  __syncthreads();
  for (int i = ty; i < 32; i += 8)
    Wt[(size_t)(n0 + i) * K + k0 + tx] = f2bf(tile[tx][i]);
}

// RoPE on packed QKV [4096][1536]: heads 0..15 = Q (scaled 0.125*log2e ->
// softmax in exp2 domain), heads 16..19 = K at col offset 1024.
__global__ void rope_qk(unsigned short* __restrict__ QKV,
                        const float* __restrict__ cosb,
                        const float* __restrict__ sinb) {
  int idx = blockIdx.x * blockDim.x + threadIdx.x;
  int d = idx & 31;
  int hh = (idx >> 5) % 20;
  int row = idx / (32 * 20);
  int t = row & 2047;
  size_t base;
  float mul;
  if (hh < 16) { base = (size_t)row * 1536 + hh * 64 + d;   mul = 0.125f * LOG2E; }
  else         { base = (size_t)row * 1536 + 1024 + (hh - 16) * 64 + d; mul = 1.0f; }
  float x1 = bf2f(QKV[base]), x2 = bf2f(QKV[base + 32]);
  float c = cosb[t * 32 + d], s = sinb[t * 32 + d];
  QKV[base]      = f2bf((x1 * c + x2 * s) * mul);
  QKV[base + 32] = f2bf((-x1 * s + x2 * c) * mul);
}

// ---------------- GEMM: C[M,N] = A[M,K] * Bt[N,K]^T ----------------
// 128x64 tile, BK=64, 4 waves (2x2), wave = 64x32 via 4x2x2 16x16x32 MFMA.
__global__ __launch_bounds__(256) void gemm_bt(
    const unsigned short* __restrict__ A, const unsigned short* __restrict__ Bt,
    void* __restrict__ Cp, int M, int N, int K, int c_f32) {
  __shared__ unsigned short As[128 * 64];   // 16 KB
  __shared__ unsigned short Bs[64 * 64];    // 8 KB
  int tid = threadIdx.x;
  int w = tid >> 6, l = tid & 63, g = l >> 4, lr = l & 15;
  int wr = w >> 1, wc = w & 1;
  int m0 = blockIdx.y * 128, n0 = blockIdx.x * 64;
  int sk = lr & 7;   // fragment-read swizzle key

  f32x4 acc[4][2] = {};

  for (int k0 = 0; k0 < K; k0 += 64) {
#pragma unroll
    for (int i = 0; i < 4; ++i) {
      int c = i * 256 + tid;             // 16B unit index, 8 units/row
      int row = c >> 3, srcu = ((c & 7) ^ (row & 7)) * 8;
      async16(A + (size_t)(m0 + row) * K + k0 + srcu, (char*)As + c * 16);
    }
#pragma unroll
    for (int i = 0; i < 2; ++i) {
      int c = i * 256 + tid;
      int row = c >> 3, srcu = ((c & 7) ^ (row & 7)) * 8;
      async16(Bt + (size_t)(n0 + row) * K + k0 + srcu, (char*)Bs + c * 16);
    }
    __syncthreads();

    s16x8 af[2][4], bfr[2][2];
#pragma unroll
    for (int ks = 0; ks < 2; ++ks) {
#pragma unroll
      for (int m = 0; m < 4; ++m)
        af[ks][m] = *(const s16x8*)(As + (wr * 64 + m * 16 + lr) * 64 +
                                    ((ks * 4 + g) ^ sk) * 8);
#pragma unroll
      for (int n = 0; n < 2; ++n)
        bfr[ks][n] = *(const s16x8*)(Bs + (wc * 32 + n * 16 + lr) * 64 +
                                     ((ks * 4 + g) ^ sk) * 8);
    }
#pragma unroll
    for (int ks = 0; ks < 2; ++ks)
#pragma unroll
      for (int m = 0; m < 4; ++m)
#pragma unroll
        for (int n = 0; n < 2; ++n)
          acc[m][n] = __builtin_amdgcn_mfma_f32_16x16x32_bf16(
              af[ks][m], bfr[ks][n], acc[m][n], 0, 0, 0);
    __syncthreads();
  }

  // C/D layout: row = (l>>4)*4 + r, col = l&15  [HW-verified]
  if (c_f32) {
    float* C = (float*)Cp;
#pragma unroll
    for (int m = 0; m < 4; ++m)
#pragma unroll
      for (int n = 0; n < 2; ++n)
#pragma unroll
        for (int r = 0; r < 4; ++r)
          C[(size_t)(m0 + wr * 64 + m * 16 + g * 4 + r) * N +
            n0 + wc * 32 + n * 16 + lr] = acc[m][n][r];
  } else {
    unsigned short* C = (unsigned short*)Cp;
#pragma unroll
    for (int m = 0; m < 4; ++m)
#pragma unroll
      for (int n = 0; n < 2; ++n)
#pragma unroll
        for (int r = 0; r < 4; ++r)
          C[(size_t)(m0 + wr * 64 + m * 16 + g * 4 + r) * N +
            n0 + wc * 32 + n * 16 + lr] = f2bf(acc[m][n][r]);
  }
}

// ---------------- flash attention (1-wave blocks, 32x32 MFMA) ----------------
// 2048 blocks x 64 threads, heavy-first: qt = 63-(n>>5) (32 q-rows), bh = n&31.
// No barriers (wave-private). K fragments direct from global (L2-resident).
// V: single 8KB LDS buffer, reg-prefetched one tile ahead.
// S^T = mfma32(K,Q): lane holds full 32-score row for q = qt*32 + (l&31);
// kv = kb*32 + (r&3)+8*(r>>2)+4*(l>>5). P built in-register (cvt_pk+shfl32).
__global__ __launch_bounds__(64) void attn_fused(
    const unsigned short* __restrict__ QKV, unsigned short* __restrict__ Y) {
  __shared__ unsigned short Vt[64 * 64];   // [d][kv], swizzled

  const int T = 2048, CS = 1536;
  int l = threadIdx.x;
  int lq = l & 31, hi = l >> 5;
  int n = blockIdx.x;
  int qt = 63 - (n >> 5);              // heavy q-tiles first
  int bh = n & 31, b = bh >> 4, h = bh & 15, kvh = h >> 2;
  int sx = l & 7;                      // == lq&7
  int q_mine = qt * 32 + lq;

  const unsigned short* Qp = QKV + (size_t)b * T * CS + h * 64;
  const unsigned short* Kp = QKV + (size_t)b * T * CS + 1024 + kvh * 64;
  const unsigned short* Vp = QKV + (size_t)b * T * CS + 1280 + kvh * 64;

  // Q B-fragments: col q = lq, k-elems = ks*16 + hi*8 + 0..7
  s16x8 qf[4];
#pragma unroll
  for (int ks = 0; ks < 4; ++ks)
    qf[ks] = *(const s16x8*)(Qp + (size_t)q_mine * CS + ks * 16 + hi * 8);

  f32x16 o0 = {}, o1 = {};
  float mrun = -1e30f, lrun = 0.f;
  int ntiles = (qt >> 1) + 1;

  // V staging decode: lane covers kv [kvi,kvi+4) x d [dc,dc+16)
  int kvi = (l & 15) * 4, dc = (l >> 4) * 16;

  // ---- prologue: V regs for tile 0 ----
  s16x8 vv[8];
#pragma unroll
  for (int k4 = 0; k4 < 4; ++k4)
#pragma unroll
    for (int hf = 0; hf < 2; ++hf)
      vv[k4 * 2 + hf] = *(const s16x8*)(Vp + (size_t)(kvi + k4) * CS + dc + hf * 8);

  for (int it = 0; it < ntiles; ++it) {
    int kv0 = it * 64;
    bool hasnext = (it + 1 < ntiles);

    // ---- K fragments direct from global (current tile) ----
    s16x8 kf0[4], kf1[4];
#pragma unroll
    for (int ks = 0; ks < 4; ++ks) {
      kf0[ks] = *(const s16x8*)(Kp + (size_t)(kv0 + lq) * CS + ks * 16 + hi * 8);
      kf1[ks] = *(const s16x8*)(Kp + (size_t)(kv0 + 32 + lq) * CS + ks * 16 + hi * 8);
    }

    // ---- write prefetched V regs -> Vt (transposed, swizzled) ----
#pragma unroll
    for (int hf = 0; hf < 2; ++hf)
#pragma unroll
      for (int j = 0; j < 8; ++j) {
        int d = dc + hf * 8 + j;
        u16x4 pk = { (unsigned short)vv[0 + hf][j], (unsigned short)vv[2 + hf][j],
                     (unsigned short)vv[4 + hf][j], (unsigned short)vv[6 + hf][j] };
        *(u16x4*)(&Vt[0] + d * 64 + (kvi ^ (j * 8))) = pk;
      }

    // ---- issue next tile's V loads (regs; consumed next iter) ----
    if (hasnext) {
      int kvn = kv0 + 64;
#pragma unroll
      for (int k4 = 0; k4 < 4; ++k4)
#pragma unroll
        for (int hf = 0; hf < 2; ++hf)
          vv[k4 * 2 + hf] =
              *(const s16x8*)(Vp + (size_t)(kvn + kvi + k4) * CS + dc + hf * 8);
    }

    // ---- S^T = K Q^T (8 mfma 32x32x16) ----
    f32x16 s0 = {}, s1 = {};
    __builtin_amdgcn_s_setprio(1);
#pragma unroll
    for (int ks = 0; ks < 4; ++ks) {
      s0 = __builtin_amdgcn_mfma_f32_32x32x16_bf16(kf0[ks], qf[ks], s0, 0, 0, 0);
      s1 = __builtin_amdgcn_mfma_f32_32x32x16_bf16(kf1[ks], qf[ks], s1, 0, 0, 0);
    }
    __builtin_amdgcn_s_setprio(0);

    if (it == ntiles - 1) {   // diagonal tile: causal mask
#pragma unroll
      for (int r = 0; r < 16; ++r) {
        int kvg = kv0 + (r & 3) + 8 * (r >> 2) + 4 * hi;
        if (kvg > q_mine) s0[r] = -1e30f;
        if (kvg + 32 > q_mine) s1[r] = -1e30f;
      }
    }

    // ---- softmax (exp2 domain): 31 in-lane fmax + 1 shfl ----
    float mt = s0[0];
#pragma unroll
    for (int r = 1; r < 16; ++r) mt = fmaxf(mt, s0[r]);
#pragma unroll
    for (int r = 0; r < 16; ++r) mt = fmaxf(mt, s1[r]);
    mt = fmaxf(mt, __shfl_xor(mt, 32, 64));

    if (__any(mt > mrun + 11.5416f)) {   // defer-max (8 nats in exp2 units)
      float mnew = fmaxf(mrun, mt);
      float corr = exp2f(mrun - mnew);
      float psum = 0.f;
#pragma unroll
      for (int r = 0; r < 16; ++r) {
        float p0 = exp2f(s0[r] - mnew); s0[r] = p0; psum += p0;
        float p1 = exp2f(s1[r] - mnew); s1[r] = p1; psum += p1;
      }
      psum += __shfl_xor(psum, 32, 64);
      lrun = lrun * corr + psum;
      mrun = mnew;
#pragma unroll
      for (int r = 0; r < 16; ++r) { o0[r] *= corr; o1[r] *= corr; }
    } else {
      float psum = 0.f;
#pragma unroll
      for (int r = 0; r < 16; ++r) {
        float p0 = exp2f(s0[r] - mrun); s0[r] = p0; psum += p0;
        float p1 = exp2f(s1[r] - mrun); s1[r] = p1; psum += p1;
      }
      psum += __shfl_xor(psum, 32, 64);
      lrun += psum;
    }

    // ---- in-register P fragments + PV (8 mfma 32x32x16) ----
    __builtin_amdgcn_s_setprio(1);
#pragma unroll
    for (int ks = 0; ks < 4; ++ks) {
      int rb = (ks & 1) * 8;
      const f32x16& sp = (ks < 2) ? s0 : s1;   // kb = ks>>1 (unrolled-const)
      unsigned int X0 = cvtpk(sp[rb + 0], sp[rb + 1]);
      unsigned int X1 = cvtpk(sp[rb + 2], sp[rb + 3]);
      unsigned int Y0 = cvtpk(sp[rb + 4], sp[rb + 5]);
      unsigned int Y1 = cvtpk(sp[rb + 6], sp[rb + 7]);
      unsigned int Z0 = hi ? X0 : Y0;
      unsigned int Z1 = hi ? X1 : Y1;
      unsigned int Zp0 = (unsigned int)__shfl_xor((int)Z0, 32, 64);
      unsigned int Zp1 = (unsigned int)__shfl_xor((int)Z1, 32, 64);
      u32x4 pw = { hi ? Zp0 : X0, hi ? Zp1 : X1,
                   hi ? Y0 : Zp0, hi ? Y1 : Zp1 };
      s16x8 pf = __builtin_bit_cast(s16x8, pw);
      int u = ((ks * 2 + hi) ^ sx) * 8;
      s16x8 vf0 = *(const s16x8*)(&Vt[0] + lq * 64 + u);
      s16x8 vf1 = *(const s16x8*)(&Vt[0] + (32 + lq) * 64 + u);
      o0 = __builtin_amdgcn_mfma_f32_32x32x16_bf16(vf0, pf, o0, 0, 0, 0);
      o1 = __builtin_amdgcn_mfma_f32_32x32x16_bf16(vf1, pf, o1, 0, 0, 0);
    }
    __builtin_amdgcn_s_setprio(0);
    // no barrier: single wave; DS pipe is in-order, next iter's Vt writes
    // cannot pass this iter's reads.
  }

  // ---- epilogue: per-lane q-local normalize; d = db*32+(r&3)+8(r>>2)+4hi ----
  float inv = 1.f / lrun;
  size_t rowoff = (size_t)(b * T + q_mine) * 1024 + h * 64;
#pragma unroll
  for (int rr = 0; rr < 4; ++rr) {
    int d0 = rr * 8 + 4 * hi;
    u16x4 w0 = { f2bf(o0[rr * 4 + 0] * inv), f2bf(o0[rr * 4 + 1] * inv),
                 f2bf(o0[rr * 4 + 2] * inv), f2bf(o0[rr * 4 + 3] * inv) };
    *(u16x4*)(Y + rowoff + d0) = w0;
    u16x4 w1 = { f2bf(o1[rr * 4 + 0] * inv), f2bf(o1[rr * 4 + 1] * inv),
                 f2bf(o1[rr * 4 + 2] * inv), f2bf(o1[rr * 4 + 3] * inv) };
    *(u16x4*)(Y + rowoff + 32 + d0) = w1;
  }
}

// ---------------- launch ----------------

extern "C" void kernel_launch(void* const* d_in, const int* in_sizes, int n_in,
                              void* d_out, int out_size, void* d_ws, size_t ws_size,
                              hipStream_t stream) {
  const float* x    = (const float*)d_in[0];
  const float* cosb = (const float*)d_in[1];
  const float* sinb = (const float*)d_in[2];
  const float* Wq   = (const float*)d_in[3];
  const float* Wk   = (const float*)d_in[4];
  const float* Wv   = (const float*)d_in[5];
  const float* Wo   = (const float*)d_in[6];
  float* out = (float*)d_out;

  // Buffer map:
  //   d_out (16 MB): QKVb [4096][1536] bf16 = 12 MB  (dead at final gemm)
  //   d_ws: xb 0..8M | Wqkvt 8..11M | Wot 11..13M ; Yb aliases xb after attn
  char* ob = (char*)d_out;
  char* ws = (char*)d_ws;
  const size_t MB = 1024 * 1024;
  unsigned short* QKVb  = (unsigned short*)(ob);
  unsigned short* xb    = (unsigned short*)(ws);
  unsigned short* Wqkvt = (unsigned short*)(ws + 8 * MB);
  unsigned short* Wot   = (unsigned short*)(ws + 11 * MB);
  unsigned short* Yb    = xb;   // x-content dead after QKV gemm

  conv_f32_to_bf16<<<4096, 256, 0, stream>>>(x, xb, 4096 * 1024);
  // pack W_qkv^T rows: [0,1024) = Wq, [1024,1280) = Wk, [1280,1536) = Wv
  transpose_conv<<<dim3(32, 32), dim3(32, 8), 0, stream>>>(Wq, Wqkvt, 1024, 1024);
  transpose_conv<<<dim3(8, 32), dim3(32, 8), 0, stream>>>(Wk, Wqkvt + (size_t)1024 * 1024, 1024, 256);
  transpose_conv<<<dim3(8, 32), dim3(32, 8), 0, stream>>>(Wv, Wqkvt + (size_t)1280 * 1024, 1024, 256);
  transpose_conv<<<dim3(32, 32), dim3(32, 8), 0, stream>>>(Wo, Wot, 1024, 1024);

  // fused QKV projection: [4096][1536] bf16
  gemm_bt<<<dim3(24, 32), 256, 0, stream>>>(xb, Wqkvt, QKVb, 4096, 1536, 1024, 0);

  // RoPE on Q (x0.125*log2e) + K in one pass
  rope_qk<<<10240, 256, 0, stream>>>(QKVb, cosb, sinb);

  // attention -> Yb bf16 [B*T][1024]
  attn_fused<<<dim3(2048), 64, 0, stream>>>(QKVb, Yb);

  // output projection (fp32, overwrites d_out)
  gemm_bt<<<dim3(16, 32), 256, 0, stream>>>(Yb, Wot, out, 4096, 1024, 1024, 1);
}